// Round 14
// baseline (75.156 us; speedup 1.0000x reference)
//
#include <hip/hip_runtime.h>

// LM-LIIF fused pipeline. R13:
//  - hyper v2: A-side lo planes dropped (feat and h1 stored as single RNE-bf16
//    LDS planes) -> MFMAs halved, LDS 52->26 KB, no split8 in the hot loops.
//    im2col staging uses 9216 = 9*1024 decomposition (no integer division).
//    F0 keeps the exact A-split (feeds query's g directly).
//  - query v11: QUAD m-chain (4 independent per-m chains, mm-loop = 2).
//  - swizzle unchanged from R10.

#define HW 96
#define NPIX (96*96)
#define CFEAT 64
#define INV192 (1.0f/192.0f)

typedef __attribute__((ext_vector_type(8))) short short8;
typedef __attribute__((ext_vector_type(4))) float f32x4;

__device__ __forceinline__ unsigned pack_bf2(float a, float b) {
    unsigned ua = __builtin_bit_cast(unsigned, a);
    unsigned ub = __builtin_bit_cast(unsigned, b);
    return (ua >> 16) | (ub & 0xffff0000u);
}
__device__ __forceinline__ float bf_hi(float a) {
    return __builtin_bit_cast(float, __builtin_bit_cast(unsigned, a) & 0xffff0000u);
}
__device__ __forceinline__ void split8(const float (&v)[8], short8& hi, short8& lo) {
    union { short8 s; unsigned u[4]; } H, L;
    #pragma unroll
    for (int p = 0; p < 4; ++p) {
        float a = v[2*p], b = v[2*p+1];
        H.u[p] = pack_bf2(a, b);
        L.u[p] = pack_bf2(a - bf_hi(a), b - bf_hi(b));
    }
    hi = H.s; lo = L.s;
}
__device__ __forceinline__ unsigned rne16(float x) {
    unsigned u = __builtin_bit_cast(unsigned, x);
    return (u + 0x7fffu + ((u >> 16) & 1u)) >> 16;
}
__device__ __forceinline__ unsigned pack_bf2_rne(float a, float b) {
    return rne16(a) | (rne16(b) << 16);
}
__device__ __forceinline__ short rne16s(float x) {
    return (short)rne16(x);
}

__device__ __forceinline__ float dpp_red16(float v) {
    int x;
    x = __builtin_amdgcn_update_dpp(0, __builtin_bit_cast(int, v), 0xB1, 0xF, 0xF, true);
    v += __builtin_bit_cast(float, x);
    x = __builtin_amdgcn_update_dpp(0, __builtin_bit_cast(int, v), 0x4E, 0xF, 0xF, true);
    v += __builtin_bit_cast(float, x);
    x = __builtin_amdgcn_update_dpp(0, __builtin_bit_cast(int, v), 0x141, 0xF, 0xF, true);
    v += __builtin_bit_cast(float, x);
    x = __builtin_amdgcn_update_dpp(0, __builtin_bit_cast(int, v), 0x140, 0xF, 0xF, true);
    v += __builtin_bit_cast(float, x);
    return v;
}

#define AXCALC(CV, SGN, II, RR)                                        \
{                                                                      \
    float e = CV + (SGN)*(1.0f/96.0f) + 1e-6f;                         \
    e = fminf(fmaxf(e, -1.0f + 1e-6f), 1.0f - 1e-6f);                  \
    II = (int)rintf((e + 1.0f) * 48.0f - 0.5f);                        \
    II = min(max(II, 0), 95);                                          \
    RR = (CV - fmaf((float)II, 0.0208333333f, -0.9895833333f)) * 96.0f;\
}

// ---------------- weight pre-swizzle (unchanged from R10) ----------------
__global__ __launch_bounds__(256) void swizzle_kernel(
    const float* __restrict__ Wh1, const float* __restrict__ Wh2,
    const float* __restrict__ W0, const float* __restrict__ W1,
    short* __restrict__ wsw)
{
    const int gid = blockIdx.x*256 + threadIdx.x;
    if (gid >= 432*64) return;
    const int f    = gid >> 6;
    const int lane = gid & 63;
    const int c    = lane & 15;
    const int kg   = lane >> 4;
    const float* W; int kt, nt, N;
    if (f < 288)      { W = Wh1; kt = f >> 4;        nt = f & 15;        N = 256; }
    else if (f < 416) { W = Wh2; kt = (f-288) >> 4;  nt = (f-288) & 15;  N = 256; }
    else if (f < 424) { W = W0;  kt = (f-416) >> 2;  nt = (f-416) & 3;   N = 64;  }
    else              { W = W1;  kt = (f-424) >> 2;  nt = (f-424) & 3;   N = 64;  }
    union { short8 s; unsigned u[4]; } H;
    #pragma unroll
    for (int p = 0; p < 4; ++p) {
        float a = W[(kt*32 + kg*8 + 2*p    )*N + nt*16 + c];
        float b = W[(kt*32 + kg*8 + 2*p + 1)*N + nt*16 + c];
        H.u[p] = pack_bf2_rne(a, b);
    }
    *(short8*)(wsw + (size_t)f*512 + lane*8) = H.s;
}

// ---------------- hyper net v2 (single RNE planes) ----------------
__global__ __launch_bounds__(512) void hyper_mfma(
    const float* __restrict__ feat,
    const float* __restrict__ cell,
    const float* __restrict__ Wh1,
    const float* __restrict__ bh1,
    const float* __restrict__ bh2,
    const float* __restrict__ b0,
    const short* __restrict__ wsw,
    float* __restrict__ mod_ws,
    float* __restrict__ f0_ws)
{
    __shared__ short AHI[72*128];     // 18 KB (RNE bf16 im2col)
    __shared__ short HHI[32*128];     //  8 KB (RNE bf16 h1)

    const int tid = threadIdx.x;
    const int blk = blockIdx.x;
    const int y   = blk / 6;
    const int x0  = (blk % 6) * 16;
    const int qbase = y*HW + x0;

    // ---- im2col stage (9216 = 9 * 1024; no divisions) ----
    for (int idx = tid; idx < 9216; idx += 512) {
        const int j   = idx >> 10;         // tap 0..8
        const int rem = idx & 1023;
        const int ch  = rem >> 4;
        const int px  = rem & 15;
        const int dy  = j / 3;             // const-range: mul-shift
        const int dx  = j - 3*dy;
        const int k   = ch*9 + j;
        const int gy  = y + dy - 1;
        const int gx  = x0 + px + dx - 1;
        float v = 0.0f;
        if (gy >= 0 && gy < HW && gx >= 0 && gx < HW)
            v = feat[ch*NPIX + gy*HW + gx];
        AHI[(k >> 3)*128 + px*8 + (k & 7)] = rne16s(v);
    }
    __syncthreads();

    const int lane = tid & 63;
    const int wid  = tid >> 6;
    const int c    = lane & 15;
    const int kg   = lane >> 4;

    const short* wh1f = wsw;
    const short* wh2f = wsw + (size_t)288*512;
    const short* w0f  = wsw + (size_t)416*512;

    // ===== F0 (waves 0..3): exact A-split (feeds query's g directly) =====
    if (wid < 4) {
        f32x4 acc0;
        const float bb = b0[wid*16 + c];
        acc0[0] = bb; acc0[1] = bb; acc0[2] = bb; acc0[3] = bb;
        #pragma unroll
        for (int kt = 0; kt < 2; ++kt) {
            float v[8];
            #pragma unroll
            for (int j = 0; j < 8; ++j)
                v[j] = feat[(kt*32 + kg*8 + j)*NPIX + y*HW + x0 + c];
            short8 Ahi, Alo;
            split8(v, Ahi, Alo);
            const short8 B = *(const short8*)(w0f + (size_t)(kt*4 + wid)*512 + lane*8);
            acc0 = __builtin_amdgcn_mfma_f32_16x16x32_bf16(Ahi, B, acc0, 0, 0, 0);
            acc0 = __builtin_amdgcn_mfma_f32_16x16x32_bf16(Alo, B, acc0, 0, 0, 0);
        }
        #pragma unroll
        for (int i = 0; i < 4; ++i)
            f0_ws[(size_t)(qbase + kg*4 + i)*64 + wid*16 + c] = acc0[i];
    }

    // ===== layer1: (16x576) @ Wh1 ; 1 MFMA per (kt,nt) =====
    f32x4 acc[2];
    #pragma unroll
    for (int nt = 0; nt < 2; ++nt) {
        const float bb = bh1[wid*32 + nt*16 + c];
        acc[nt][0] = bb; acc[nt][1] = bb; acc[nt][2] = bb; acc[nt][3] = bb;
    }
    #pragma unroll
    for (int kt = 0; kt < 18; ++kt) {
        const short8 A = *(const short8*)&AHI[(kt*4 + kg)*128 + c*8];
        #pragma unroll
        for (int nt = 0; nt < 2; ++nt) {
            const short8 B = *(const short8*)(wh1f + (size_t)(kt*16 + wid*2 + nt)*512 + lane*8);
            acc[nt] = __builtin_amdgcn_mfma_f32_16x16x32_bf16(A, B, acc[nt], 0, 0, 0);
        }
    }
    {
        float rc0v[4], rc1v[4];
        #pragma unroll
        for (int i = 0; i < 4; ++i) {
            const int q = qbase + kg*4 + i;
            const float2 ce = ((const float2*)cell)[q];
            rc0v[i] = ce.x * 96.0f;
            rc1v[i] = ce.y * 96.0f;
        }
        #pragma unroll
        for (int nt = 0; nt < 2; ++nt) {
            const int n = wid*32 + nt*16 + c;
            const float w5 = Wh1[576*256 + n];
            const float w6 = Wh1[577*256 + n];
            #pragma unroll
            for (int i = 0; i < 4; ++i) {
                float hv = acc[nt][i] + rc0v[i]*w5 + rc1v[i]*w6;
                hv = fmaxf(hv, 0.0f);
                HHI[(n >> 3)*128 + (kg*4 + i)*8 + (n & 7)] = rne16s(hv);
            }
        }
    }
    __syncthreads();

    // ===== layer2: (16x256) @ Wh2 =====
    f32x4 acc2[2];
    #pragma unroll
    for (int nt = 0; nt < 2; ++nt) {
        const float bb = bh2[wid*32 + nt*16 + c];
        acc2[nt][0] = bb; acc2[nt][1] = bb; acc2[nt][2] = bb; acc2[nt][3] = bb;
    }
    #pragma unroll
    for (int kt = 0; kt < 8; ++kt) {
        const short8 A = *(const short8*)&HHI[(kt*4 + kg)*128 + c*8];
        #pragma unroll
        for (int nt = 0; nt < 2; ++nt) {
            const short8 B = *(const short8*)(wh2f + (size_t)(kt*16 + wid*2 + nt)*512 + lane*8);
            acc2[nt] = __builtin_amdgcn_mfma_f32_16x16x32_bf16(A, B, acc2[nt], 0, 0, 0);
        }
    }
    #pragma unroll
    for (int nt = 0; nt < 2; ++nt) {
        #pragma unroll
        for (int i = 0; i < 4; ++i)
            mod_ws[(size_t)(qbase + kg*4 + i)*256 + wid*32 + nt*16 + c] = acc2[nt][i];
    }
}

// ---------------- query kernel v11 (quad m-chain) ----------------
#define ROWQ 324

#define EPI_CALC(S, QY)                                                     \
    const float cy##S = ((float)(QY) + 0.5f) * INV192 - 1.0f;               \
    int iym##S, iyp##S; float r0m##S, r0p##S;                               \
    AXCALC(cy##S, -1.0f, iym##S, r0m##S)                                    \
    AXCALC(cy##S,  1.0f, iyp##S, r0p##S)                                    \
    const int rym##S = (iym##S - ly0)*4 - lx0;                              \
    const int ryp##S = (iyp##S - ly0)*4 - lx0;                              \
    const int lrA##S[4] = { rym##S + ixm, rym##S + ixp,                     \
                            ryp##S + ixm, ryp##S + ixp };                   \
    const float a0##S = fabsf(r0m##S*r1m) + 1e-9f;                          \
    const float a1##S = fabsf(r0m##S*r1p) + 1e-9f;                          \
    const float a2##S = fabsf(r0p##S*r1m) + 1e-9f;                          \
    const float a3##S = fabsf(r0p##S*r1p) + 1e-9f;                          \
    const float invt##S = 1.0f / (a0##S + a1##S + a2##S + a3##S);           \
    const float wgt##S[4] = { a3##S*invt##S, a2##S*invt##S,                 \
                              a1##S*invt##S, a0##S*invt##S };

#define ALOAD(S)                                                            \
    int iyA##S; float r0A##S;                                               \
    AXCALC(cy##S, vxA, iyA##S, r0A##S)                                      \
    const float* rowp##S = smem + ((iyA##S - ly0)*4 + ixAc) * ROWQ;         \
    float4 ga##S[2], gb##S[2], u0a##S[2], u0b##S[2], u1a##S[2], u1b##S[2];  \
    _Pragma("unroll")                                                       \
    for (int kt = 0; kt < 2; ++kt) {                                        \
        const int kb = kt*32 + kg*8;                                        \
        ga##S[kt]  = *(const float4*)(rowp##S + kb);                        \
        gb##S[kt]  = *(const float4*)(rowp##S + kb + 4);                    \
        u0a##S[kt] = *(const float4*)(rowp##S + 64  + kb);                  \
        u0b##S[kt] = *(const float4*)(rowp##S + 64  + kb + 4);              \
        u1a##S[kt] = *(const float4*)(rowp##S + 128 + kb);                  \
        u1b##S[kt] = *(const float4*)(rowp##S + 128 + kb + 4);              \
    }

#define EPI_LOAD(S)                                                         \
    float4 sc2v##S[4], sh2v##S[4];                                          \
    _Pragma("unroll")                                                       \
    for (int i = 0; i < 4; ++i) {                                           \
        sc2v##S[i] = *(const float4*)(smem + lrA##S[i]*ROWQ + 192 + c*4);   \
        sh2v##S[i] = *(const float4*)(smem + lrA##S[i]*ROWQ + 256 + c*4);   \
    }

#define APACK(S)                                                            \
    short8 Afr##S[2];                                                       \
    _Pragma("unroll")                                                       \
    for (int kt = 0; kt < 2; ++kt) {                                        \
        float g[8]  = {ga##S[kt].x, ga##S[kt].y, ga##S[kt].z, ga##S[kt].w,  \
                       gb##S[kt].x, gb##S[kt].y, gb##S[kt].z, gb##S[kt].w}; \
        float u0[8] = {u0a##S[kt].x, u0a##S[kt].y, u0a##S[kt].z, u0a##S[kt].w, \
                       u0b##S[kt].x, u0b##S[kt].y, u0b##S[kt].z, u0b##S[kt].w}; \
        float u1[8] = {u1a##S[kt].x, u1a##S[kt].y, u1a##S[kt].z, u1a##S[kt].w, \
                       u1b##S[kt].x, u1b##S[kt].y, u1b##S[kt].z, u1b##S[kt].w}; \
        union { short8 s; unsigned u[4]; } P;                               \
        _Pragma("unroll")                                                   \
        for (int p = 0; p < 4; ++p) {                                       \
            float h0 = fmaxf(fmaf(r1A, u1[2*p],   fmaf(r0A##S, u0[2*p],   g[2*p]  )), 0.f); \
            float h1 = fmaxf(fmaf(r1A, u1[2*p+1], fmaf(r0A##S, u0[2*p+1], g[2*p+1])), 0.f); \
            P.u[p] = pack_bf2_rne(h0, h1);                                  \
        }                                                                   \
        Afr##S[kt] = P.s;                                                   \
    }

#define MFMA_C(S)                                                           \
    f32x4 acc##S[4];                                                        \
    _Pragma("unroll")                                                       \
    for (int nt = 0; nt < 4; ++nt) {                                        \
        f32x4 z = {b1c[nt], b1c[nt], b1c[nt], b1c[nt]};                     \
        acc##S[nt] = z;                                                     \
        _Pragma("unroll")                                                   \
        for (int kt = 0; kt < 2; ++kt)                                      \
            acc##S[nt] = __builtin_amdgcn_mfma_f32_16x16x32_bf16(Afr##S[kt], Bh[nt][kt], acc##S[nt], 0, 0, 0); \
    }

#define EPIL(S, QY)                                                         \
    {                                                                       \
        float p0 = 0.f, p1 = 0.f, p2 = 0.f;                                 \
        _Pragma("unroll")                                                   \
        for (int i = 0; i < 4; ++i) {                                       \
            const float wi = wgt##S[i];                                     \
            float s0 = 0.f, s1 = 0.f, s2 = 0.f;                             \
            _Pragma("unroll")                                               \
            for (int nt = 0; nt < 4; ++nt) {                                \
                const float sc2 = (nt==0)?sc2v##S[i].x:(nt==1)?sc2v##S[i].y:(nt==2)?sc2v##S[i].z:sc2v##S[i].w; \
                const float sh2 = (nt==0)?sh2v##S[i].x:(nt==1)?sh2v##S[i].y:(nt==2)?sh2v##S[i].z:sh2v##S[i].w; \
                const float v = fmaxf(fmaf(acc##S[nt][i], sc2, sh2), 0.f);  \
                s0 = fmaf(v, w2r[nt][0], s0);                               \
                s1 = fmaf(v, w2r[nt][1], s1);                               \
                s2 = fmaf(v, w2r[nt][2], s2);                               \
            }                                                               \
            p0 = fmaf(s0, wi, p0);                                          \
            p1 = fmaf(s1, wi, p1);                                          \
            p2 = fmaf(s2, wi, p2);                                          \
        }                                                                   \
        p0 = dpp_red16(p0); p1 = dpp_red16(p1); p2 = dpp_red16(p2);         \
        if (c < 3) {                                                        \
            const int qE = (QY)*384 + Xw + kg;                              \
            const float ov = (c == 0) ? p0 + b2v0 : (c == 1) ? p1 + b2v1 : p2 + b2v2; \
            out[(size_t)qE*3 + c] = ov;                                     \
        }                                                                   \
    }

__global__ __launch_bounds__(256, 2) void query_kernel_v11(
    const float* __restrict__ cell,
    const float* __restrict__ W0,
    const short* __restrict__ wsw,
    const float* __restrict__ b1,
    const float* __restrict__ W2,
    const float* __restrict__ b2,
    const float* __restrict__ mod_ws,
    const float* __restrict__ f0_ws,
    float* __restrict__ out)
{
    __shared__ float smem[24*ROWQ];    // 31.1 KB

    const int tid = threadIdx.x;
    const int bX  = blockIdx.x % 48;
    const int bY  = blockIdx.x / 48;
    const int X0  = bX * 8;
    const int Y0  = bY * 16;
    const int lx0 = bX*2 - 1;          // 4 latent cols
    const int ly0 = bY*4 - 1;          // 6 latent rows

    const float rc0 = cell[0] * 96.0f;
    const float rc1 = cell[1] * 96.0f;

    const float4* w64p = (const float4*)(W0 + 64*64);
    const float4* w65p = (const float4*)(W0 + 65*64);
    const float4* w66p = (const float4*)(W0 + 66*64);
    const float4* w67p = (const float4*)(W0 + 67*64);

    // ---- stage 6x4 latent patch: 24 rows x 64 items ----
    for (int idx = tid; idx < 1536; idx += 256) {
        const int r  = idx >> 6;
        const int o  = idx & 63;
        const int ry = r >> 2;
        const int rx = r & 3;
        const int gy = min(max(ly0 + ry, 0), 95);
        const int gx = min(max(lx0 + rx, 0), 95);
        const int src = gy*96 + gx;
        const float4* modv = (const float4*)(mod_ws + (size_t)src*256);
        if (o < 16) {
            const float4 f0 = ((const float4*)(f0_ws + (size_t)src*64))[o];
            const float4 s1 = modv[o];
            const float4 t1 = modv[32 + o];
            const float4 a  = w66p[o];
            const float4 b  = w67p[o];
            float4 v;
            v.x = fmaf(s1.x, fmaf(rc1, b.x, fmaf(rc0, a.x, f0.x)), t1.x);
            v.y = fmaf(s1.y, fmaf(rc1, b.y, fmaf(rc0, a.y, f0.y)), t1.y);
            v.z = fmaf(s1.z, fmaf(rc1, b.z, fmaf(rc0, a.z, f0.z)), t1.z);
            v.w = fmaf(s1.w, fmaf(rc1, b.w, fmaf(rc0, a.w, f0.w)), t1.w);
            *(float4*)(smem + r*ROWQ + o*4) = v;
        } else if (o < 32) {
            const int oo = o - 16;
            const float4 s1 = modv[oo];
            const float4 w  = w64p[oo];
            float4 v = {s1.x*w.x, s1.y*w.y, s1.z*w.z, s1.w*w.w};
            *(float4*)(smem + r*ROWQ + 64 + oo*4) = v;
        } else if (o < 48) {
            const int oo = o - 32;
            const float4 s1 = modv[oo];
            const float4 w  = w65p[oo];
            float4 v = {s1.x*w.x, s1.y*w.y, s1.z*w.z, s1.w*w.w};
            *(float4*)(smem + r*ROWQ + 128 + oo*4) = v;
        } else {
            const int oo = o - 48;             // 0..15
            const float4 s2 = modv[16 + oo];
            const float4 h2 = modv[48 + oo];
            #pragma unroll
            for (int j = 0; j < 4; ++j) {
                const int col = oo*4 + j;
                const int cc  = col & 15;
                const int nt  = col >> 4;
                const float sv = (j==0)?s2.x:(j==1)?s2.y:(j==2)?s2.z:s2.w;
                const float hv = (j==0)?h2.x:(j==1)?h2.y:(j==2)?h2.z:h2.w;
                smem[r*ROWQ + 192 + cc*4 + nt] = sv;
                smem[r*ROWQ + 256 + cc*4 + nt] = hv;
            }
        }
    }

    const int lane = tid & 63;
    const int wid  = tid >> 6;
    const int c    = lane & 15;
    const int kg   = lane >> 4;

    // per-wave constants: W1 frags from wsw (8 b128 loads)
    const short* w1f = wsw + (size_t)424*512;
    short8 Bh[4][2];
    #pragma unroll
    for (int kt = 0; kt < 2; ++kt)
        #pragma unroll
        for (int nt = 0; nt < 4; ++nt)
            Bh[nt][kt] = *(const short8*)(w1f + (size_t)(kt*4 + nt)*512 + lane*8);

    float b1c[4];
    float w2r[4][3];
    #pragma unroll
    for (int nt = 0; nt < 4; ++nt) {
        b1c[nt] = b1[nt*16 + c];
        w2r[nt][0] = W2[(nt*16 + c)*3 + 0];
        w2r[nt][1] = W2[(nt*16 + c)*3 + 1];
        w2r[nt][2] = W2[(nt*16 + c)*3 + 2];
    }
    const float b2v0 = b2[0], b2v1 = b2[1], b2v2 = b2[2];

    __syncthreads();

    const int Xw   = X0 + (wid & 1)*4;
    const int Yw   = Y0 + (wid >> 1)*8;
    const int qxA  = c >> 2;
    const int tapA = c & 3;
    const float vxA = (tapA < 2) ? -1.0f : 1.0f;
    const float vyA = (tapA & 1) ? 1.0f : -1.0f;

    // m-invariant x-axis tap math
    const float cxA = ((float)(Xw + qxA) + 0.5f) * INV192 - 1.0f;
    const float cxE = ((float)(Xw + kg)  + 0.5f) * INV192 - 1.0f;
    int ixA; float r1A;
    AXCALC(cxA, vyA, ixA, r1A)
    const int ixAc = ixA - lx0;
    int ixm, ixp; float r1m, r1p;
    AXCALC(cxE, -1.0f, ixm, r1m)
    AXCALC(cxE,  1.0f, ixp, r1p)

    for (int mm = 0; mm < 2; ++mm) {
        const int qyA_ = Yw + 4*mm + 0;
        const int qyB_ = Yw + 4*mm + 1;
        const int qyC_ = Yw + 4*mm + 2;
        const int qyD_ = Yw + 4*mm + 3;

        EPI_CALC(A, qyA_)
        EPI_CALC(B, qyB_)
        EPI_CALC(C, qyC_)
        EPI_CALC(D, qyD_)
        ALOAD(A)
        ALOAD(B)
        ALOAD(C)
        ALOAD(D)
        EPI_LOAD(A)
        EPI_LOAD(B)
        EPI_LOAD(C)
        EPI_LOAD(D)
        APACK(A)
        APACK(B)
        APACK(C)
        APACK(D)
        MFMA_C(A)
        MFMA_C(B)
        MFMA_C(C)
        MFMA_C(D)
        EPIL(A, qyA_)
        EPIL(B, qyB_)
        EPIL(C, qyC_)
        EPIL(D, qyD_)
    }
}

extern "C" void kernel_launch(void* const* d_in, const int* in_sizes, int n_in,
                              void* d_out, int out_size, void* d_ws, size_t ws_size,
                              hipStream_t stream) {
    const float* feat  = (const float*)d_in[0];
    const float* cell  = (const float*)d_in[2];
    const float* Wh1   = (const float*)d_in[3];
    const float* bh1   = (const float*)d_in[4];
    const float* Wh2   = (const float*)d_in[5];
    const float* bh2   = (const float*)d_in[6];
    const float* W0    = (const float*)d_in[7];
    const float* b0    = (const float*)d_in[8];
    const float* W1    = (const float*)d_in[9];
    const float* b1    = (const float*)d_in[10];
    const float* W2    = (const float*)d_in[11];
    const float* b2    = (const float*)d_in[12];
    float* out = (float*)d_out;

    float* mod_ws = (float*)d_ws;                         // 9216*256 f32
    float* f0_ws  = (float*)d_ws + 9216*256;              // 9216*64  f32
    short* wsw    = (short*)((char*)d_ws + 11796480);     // 432 frags * 1024 B

    swizzle_kernel<<<dim3(108), dim3(256), 0, stream>>>(Wh1, Wh2, W0, W1, wsw);
    hyper_mfma<<<dim3(576), dim3(512), 0, stream>>>(
        feat, cell, Wh1, bh1, bh2, b0, wsw, mod_ws, f0_ws);
    query_kernel_v11<<<dim3(1152), dim3(256), 0, stream>>>(
        cell, W0, wsw, b1, W2, b2, mod_ws, f0_ws, out);
}

// Round 15
// 66.780 us; speedup vs baseline: 1.1254x; 1.1254x over previous
//
#include <hip/hip_runtime.h>

// LM-LIIF fused pipeline. R14: best-of recombination.
//  - query v10 (R12's dual m-chain, the 45.2 µs config) restored verbatim:
//    quad-chain (R13) regressed via VGPR 124 / occupancy 16% — ILP/TLP peak
//    is at dual.
//  - hyper v2 (R13's single-RNE planes) kept: absmax unchanged, ~14 µs.
//  - swizzle unchanged from R10.

#define HW 96
#define NPIX (96*96)
#define CFEAT 64
#define INV192 (1.0f/192.0f)

typedef __attribute__((ext_vector_type(8))) short short8;
typedef __attribute__((ext_vector_type(4))) float f32x4;

__device__ __forceinline__ unsigned pack_bf2(float a, float b) {
    unsigned ua = __builtin_bit_cast(unsigned, a);
    unsigned ub = __builtin_bit_cast(unsigned, b);
    return (ua >> 16) | (ub & 0xffff0000u);
}
__device__ __forceinline__ float bf_hi(float a) {
    return __builtin_bit_cast(float, __builtin_bit_cast(unsigned, a) & 0xffff0000u);
}
__device__ __forceinline__ void split8(const float (&v)[8], short8& hi, short8& lo) {
    union { short8 s; unsigned u[4]; } H, L;
    #pragma unroll
    for (int p = 0; p < 4; ++p) {
        float a = v[2*p], b = v[2*p+1];
        H.u[p] = pack_bf2(a, b);
        L.u[p] = pack_bf2(a - bf_hi(a), b - bf_hi(b));
    }
    hi = H.s; lo = L.s;
}
__device__ __forceinline__ unsigned rne16(float x) {
    unsigned u = __builtin_bit_cast(unsigned, x);
    return (u + 0x7fffu + ((u >> 16) & 1u)) >> 16;
}
__device__ __forceinline__ unsigned pack_bf2_rne(float a, float b) {
    return rne16(a) | (rne16(b) << 16);
}
__device__ __forceinline__ short rne16s(float x) {
    return (short)rne16(x);
}

__device__ __forceinline__ float dpp_red16(float v) {
    int x;
    x = __builtin_amdgcn_update_dpp(0, __builtin_bit_cast(int, v), 0xB1, 0xF, 0xF, true);
    v += __builtin_bit_cast(float, x);
    x = __builtin_amdgcn_update_dpp(0, __builtin_bit_cast(int, v), 0x4E, 0xF, 0xF, true);
    v += __builtin_bit_cast(float, x);
    x = __builtin_amdgcn_update_dpp(0, __builtin_bit_cast(int, v), 0x141, 0xF, 0xF, true);
    v += __builtin_bit_cast(float, x);
    x = __builtin_amdgcn_update_dpp(0, __builtin_bit_cast(int, v), 0x140, 0xF, 0xF, true);
    v += __builtin_bit_cast(float, x);
    return v;
}

#define AXCALC(CV, SGN, II, RR)                                        \
{                                                                      \
    float e = CV + (SGN)*(1.0f/96.0f) + 1e-6f;                         \
    e = fminf(fmaxf(e, -1.0f + 1e-6f), 1.0f - 1e-6f);                  \
    II = (int)rintf((e + 1.0f) * 48.0f - 0.5f);                        \
    II = min(max(II, 0), 95);                                          \
    RR = (CV - fmaf((float)II, 0.0208333333f, -0.9895833333f)) * 96.0f;\
}

// ---------------- weight pre-swizzle (unchanged from R10) ----------------
__global__ __launch_bounds__(256) void swizzle_kernel(
    const float* __restrict__ Wh1, const float* __restrict__ Wh2,
    const float* __restrict__ W0, const float* __restrict__ W1,
    short* __restrict__ wsw)
{
    const int gid = blockIdx.x*256 + threadIdx.x;
    if (gid >= 432*64) return;
    const int f    = gid >> 6;
    const int lane = gid & 63;
    const int c    = lane & 15;
    const int kg   = lane >> 4;
    const float* W; int kt, nt, N;
    if (f < 288)      { W = Wh1; kt = f >> 4;        nt = f & 15;        N = 256; }
    else if (f < 416) { W = Wh2; kt = (f-288) >> 4;  nt = (f-288) & 15;  N = 256; }
    else if (f < 424) { W = W0;  kt = (f-416) >> 2;  nt = (f-416) & 3;   N = 64;  }
    else              { W = W1;  kt = (f-424) >> 2;  nt = (f-424) & 3;   N = 64;  }
    union { short8 s; unsigned u[4]; } H;
    #pragma unroll
    for (int p = 0; p < 4; ++p) {
        float a = W[(kt*32 + kg*8 + 2*p    )*N + nt*16 + c];
        float b = W[(kt*32 + kg*8 + 2*p + 1)*N + nt*16 + c];
        H.u[p] = pack_bf2_rne(a, b);
    }
    *(short8*)(wsw + (size_t)f*512 + lane*8) = H.s;
}

// ---------------- hyper net v2 (single RNE planes, from R13) ----------------
__global__ __launch_bounds__(512) void hyper_mfma(
    const float* __restrict__ feat,
    const float* __restrict__ cell,
    const float* __restrict__ Wh1,
    const float* __restrict__ bh1,
    const float* __restrict__ bh2,
    const float* __restrict__ b0,
    const short* __restrict__ wsw,
    float* __restrict__ mod_ws,
    float* __restrict__ f0_ws)
{
    __shared__ short AHI[72*128];     // 18 KB (RNE bf16 im2col)
    __shared__ short HHI[32*128];     //  8 KB (RNE bf16 h1)

    const int tid = threadIdx.x;
    const int blk = blockIdx.x;
    const int y   = blk / 6;
    const int x0  = (blk % 6) * 16;
    const int qbase = y*HW + x0;

    // ---- im2col stage (9216 = 9 * 1024; no divisions) ----
    for (int idx = tid; idx < 9216; idx += 512) {
        const int j   = idx >> 10;         // tap 0..8
        const int rem = idx & 1023;
        const int ch  = rem >> 4;
        const int px  = rem & 15;
        const int dy  = j / 3;
        const int dx  = j - 3*dy;
        const int k   = ch*9 + j;
        const int gy  = y + dy - 1;
        const int gx  = x0 + px + dx - 1;
        float v = 0.0f;
        if (gy >= 0 && gy < HW && gx >= 0 && gx < HW)
            v = feat[ch*NPIX + gy*HW + gx];
        AHI[(k >> 3)*128 + px*8 + (k & 7)] = rne16s(v);
    }
    __syncthreads();

    const int lane = tid & 63;
    const int wid  = tid >> 6;
    const int c    = lane & 15;
    const int kg   = lane >> 4;

    const short* wh1f = wsw;
    const short* wh2f = wsw + (size_t)288*512;
    const short* w0f  = wsw + (size_t)416*512;

    // ===== F0 (waves 0..3): exact A-split (feeds query's g directly) =====
    if (wid < 4) {
        f32x4 acc0;
        const float bb = b0[wid*16 + c];
        acc0[0] = bb; acc0[1] = bb; acc0[2] = bb; acc0[3] = bb;
        #pragma unroll
        for (int kt = 0; kt < 2; ++kt) {
            float v[8];
            #pragma unroll
            for (int j = 0; j < 8; ++j)
                v[j] = feat[(kt*32 + kg*8 + j)*NPIX + y*HW + x0 + c];
            short8 Ahi, Alo;
            split8(v, Ahi, Alo);
            const short8 B = *(const short8*)(w0f + (size_t)(kt*4 + wid)*512 + lane*8);
            acc0 = __builtin_amdgcn_mfma_f32_16x16x32_bf16(Ahi, B, acc0, 0, 0, 0);
            acc0 = __builtin_amdgcn_mfma_f32_16x16x32_bf16(Alo, B, acc0, 0, 0, 0);
        }
        #pragma unroll
        for (int i = 0; i < 4; ++i)
            f0_ws[(size_t)(qbase + kg*4 + i)*64 + wid*16 + c] = acc0[i];
    }

    // ===== layer1: (16x576) @ Wh1 ; 1 MFMA per (kt,nt) =====
    f32x4 acc[2];
    #pragma unroll
    for (int nt = 0; nt < 2; ++nt) {
        const float bb = bh1[wid*32 + nt*16 + c];
        acc[nt][0] = bb; acc[nt][1] = bb; acc[nt][2] = bb; acc[nt][3] = bb;
    }
    #pragma unroll
    for (int kt = 0; kt < 18; ++kt) {
        const short8 A = *(const short8*)&AHI[(kt*4 + kg)*128 + c*8];
        #pragma unroll
        for (int nt = 0; nt < 2; ++nt) {
            const short8 B = *(const short8*)(wh1f + (size_t)(kt*16 + wid*2 + nt)*512 + lane*8);
            acc[nt] = __builtin_amdgcn_mfma_f32_16x16x32_bf16(A, B, acc[nt], 0, 0, 0);
        }
    }
    {
        float rc0v[4], rc1v[4];
        #pragma unroll
        for (int i = 0; i < 4; ++i) {
            const int q = qbase + kg*4 + i;
            const float2 ce = ((const float2*)cell)[q];
            rc0v[i] = ce.x * 96.0f;
            rc1v[i] = ce.y * 96.0f;
        }
        #pragma unroll
        for (int nt = 0; nt < 2; ++nt) {
            const int n = wid*32 + nt*16 + c;
            const float w5 = Wh1[576*256 + n];
            const float w6 = Wh1[577*256 + n];
            #pragma unroll
            for (int i = 0; i < 4; ++i) {
                float hv = acc[nt][i] + rc0v[i]*w5 + rc1v[i]*w6;
                hv = fmaxf(hv, 0.0f);
                HHI[(n >> 3)*128 + (kg*4 + i)*8 + (n & 7)] = rne16s(hv);
            }
        }
    }
    __syncthreads();

    // ===== layer2: (16x256) @ Wh2 =====
    f32x4 acc2[2];
    #pragma unroll
    for (int nt = 0; nt < 2; ++nt) {
        const float bb = bh2[wid*32 + nt*16 + c];
        acc2[nt][0] = bb; acc2[nt][1] = bb; acc2[nt][2] = bb; acc2[nt][3] = bb;
    }
    #pragma unroll
    for (int kt = 0; kt < 8; ++kt) {
        const short8 A = *(const short8*)&HHI[(kt*4 + kg)*128 + c*8];
        #pragma unroll
        for (int nt = 0; nt < 2; ++nt) {
            const short8 B = *(const short8*)(wh2f + (size_t)(kt*16 + wid*2 + nt)*512 + lane*8);
            acc2[nt] = __builtin_amdgcn_mfma_f32_16x16x32_bf16(A, B, acc2[nt], 0, 0, 0);
        }
    }
    #pragma unroll
    for (int nt = 0; nt < 2; ++nt) {
        #pragma unroll
        for (int i = 0; i < 4; ++i)
            mod_ws[(size_t)(qbase + kg*4 + i)*256 + wid*32 + nt*16 + c] = acc2[nt][i];
    }
}

// ---------------- query kernel v10 (dual m-chain, from R12) ----------------
#define ROWQ 324

#define EPI_CALC(S, QY)                                                     \
    const float cy##S = ((float)(QY) + 0.5f) * INV192 - 1.0f;               \
    int iym##S, iyp##S; float r0m##S, r0p##S;                               \
    AXCALC(cy##S, -1.0f, iym##S, r0m##S)                                    \
    AXCALC(cy##S,  1.0f, iyp##S, r0p##S)                                    \
    const int rym##S = (iym##S - ly0)*4 - lx0;                              \
    const int ryp##S = (iyp##S - ly0)*4 - lx0;                              \
    const int lrA##S[4] = { rym##S + ixm, rym##S + ixp,                     \
                            ryp##S + ixm, ryp##S + ixp };                   \
    const float a0##S = fabsf(r0m##S*r1m) + 1e-9f;                          \
    const float a1##S = fabsf(r0m##S*r1p) + 1e-9f;                          \
    const float a2##S = fabsf(r0p##S*r1m) + 1e-9f;                          \
    const float a3##S = fabsf(r0p##S*r1p) + 1e-9f;                          \
    const float invt##S = 1.0f / (a0##S + a1##S + a2##S + a3##S);           \
    const float wgt##S[4] = { a3##S*invt##S, a2##S*invt##S,                 \
                              a1##S*invt##S, a0##S*invt##S };

#define ALOAD(S)                                                            \
    int iyA##S; float r0A##S;                                               \
    AXCALC(cy##S, vxA, iyA##S, r0A##S)                                      \
    const float* rowp##S = smem + ((iyA##S - ly0)*4 + ixAc) * ROWQ;         \
    float4 ga##S[2], gb##S[2], u0a##S[2], u0b##S[2], u1a##S[2], u1b##S[2];  \
    _Pragma("unroll")                                                       \
    for (int kt = 0; kt < 2; ++kt) {                                        \
        const int kb = kt*32 + kg*8;                                        \
        ga##S[kt]  = *(const float4*)(rowp##S + kb);                        \
        gb##S[kt]  = *(const float4*)(rowp##S + kb + 4);                    \
        u0a##S[kt] = *(const float4*)(rowp##S + 64  + kb);                  \
        u0b##S[kt] = *(const float4*)(rowp##S + 64  + kb + 4);              \
        u1a##S[kt] = *(const float4*)(rowp##S + 128 + kb);                  \
        u1b##S[kt] = *(const float4*)(rowp##S + 128 + kb + 4);              \
    }

#define EPI_LOAD(S)                                                         \
    float4 sc2v##S[4], sh2v##S[4];                                          \
    _Pragma("unroll")                                                       \
    for (int i = 0; i < 4; ++i) {                                           \
        sc2v##S[i] = *(const float4*)(smem + lrA##S[i]*ROWQ + 192 + c*4);   \
        sh2v##S[i] = *(const float4*)(smem + lrA##S[i]*ROWQ + 256 + c*4);   \
    }

#define APACK(S)                                                            \
    short8 Afr##S[2];                                                       \
    _Pragma("unroll")                                                       \
    for (int kt = 0; kt < 2; ++kt) {                                        \
        float g[8]  = {ga##S[kt].x, ga##S[kt].y, ga##S[kt].z, ga##S[kt].w,  \
                       gb##S[kt].x, gb##S[kt].y, gb##S[kt].z, gb##S[kt].w}; \
        float u0[8] = {u0a##S[kt].x, u0a##S[kt].y, u0a##S[kt].z, u0a##S[kt].w, \
                       u0b##S[kt].x, u0b##S[kt].y, u0b##S[kt].z, u0b##S[kt].w}; \
        float u1[8] = {u1a##S[kt].x, u1a##S[kt].y, u1a##S[kt].z, u1a##S[kt].w, \
                       u1b##S[kt].x, u1b##S[kt].y, u1b##S[kt].z, u1b##S[kt].w}; \
        union { short8 s; unsigned u[4]; } P;                               \
        _Pragma("unroll")                                                   \
        for (int p = 0; p < 4; ++p) {                                       \
            float h0 = fmaxf(fmaf(r1A, u1[2*p],   fmaf(r0A##S, u0[2*p],   g[2*p]  )), 0.f); \
            float h1 = fmaxf(fmaf(r1A, u1[2*p+1], fmaf(r0A##S, u0[2*p+1], g[2*p+1])), 0.f); \
            P.u[p] = pack_bf2_rne(h0, h1);                                  \
        }                                                                   \
        Afr##S[kt] = P.s;                                                   \
    }

#define MFMA_C(S)                                                           \
    f32x4 acc##S[4];                                                        \
    _Pragma("unroll")                                                       \
    for (int nt = 0; nt < 4; ++nt) {                                        \
        f32x4 z = {b1c[nt], b1c[nt], b1c[nt], b1c[nt]};                     \
        acc##S[nt] = z;                                                     \
        _Pragma("unroll")                                                   \
        for (int kt = 0; kt < 2; ++kt)                                      \
            acc##S[nt] = __builtin_amdgcn_mfma_f32_16x16x32_bf16(Afr##S[kt], Bh[nt][kt], acc##S[nt], 0, 0, 0); \
    }

#define EPIL(S, QY)                                                         \
    {                                                                       \
        float p0 = 0.f, p1 = 0.f, p2 = 0.f;                                 \
        _Pragma("unroll")                                                   \
        for (int i = 0; i < 4; ++i) {                                       \
            const float wi = wgt##S[i];                                     \
            float s0 = 0.f, s1 = 0.f, s2 = 0.f;                             \
            _Pragma("unroll")                                               \
            for (int nt = 0; nt < 4; ++nt) {                                \
                const float sc2 = (nt==0)?sc2v##S[i].x:(nt==1)?sc2v##S[i].y:(nt==2)?sc2v##S[i].z:sc2v##S[i].w; \
                const float sh2 = (nt==0)?sh2v##S[i].x:(nt==1)?sh2v##S[i].y:(nt==2)?sh2v##S[i].z:sh2v##S[i].w; \
                const float v = fmaxf(fmaf(acc##S[nt][i], sc2, sh2), 0.f);  \
                s0 = fmaf(v, w2r[nt][0], s0);                               \
                s1 = fmaf(v, w2r[nt][1], s1);                               \
                s2 = fmaf(v, w2r[nt][2], s2);                               \
            }                                                               \
            p0 = fmaf(s0, wi, p0);                                          \
            p1 = fmaf(s1, wi, p1);                                          \
            p2 = fmaf(s2, wi, p2);                                          \
        }                                                                   \
        p0 = dpp_red16(p0); p1 = dpp_red16(p1); p2 = dpp_red16(p2);         \
        if (c < 3) {                                                        \
            const int qE = (QY)*384 + Xw + kg;                              \
            const float ov = (c == 0) ? p0 + b2v0 : (c == 1) ? p1 + b2v1 : p2 + b2v2; \
            out[(size_t)qE*3 + c] = ov;                                     \
        }                                                                   \
    }

__global__ __launch_bounds__(256, 2) void query_kernel_v10(
    const float* __restrict__ cell,
    const float* __restrict__ W0,
    const short* __restrict__ wsw,
    const float* __restrict__ b1,
    const float* __restrict__ W2,
    const float* __restrict__ b2,
    const float* __restrict__ mod_ws,
    const float* __restrict__ f0_ws,
    float* __restrict__ out)
{
    __shared__ float smem[24*ROWQ];    // 31.1 KB

    const int tid = threadIdx.x;
    const int bX  = blockIdx.x % 48;
    const int bY  = blockIdx.x / 48;
    const int X0  = bX * 8;
    const int Y0  = bY * 16;
    const int lx0 = bX*2 - 1;          // 4 latent cols
    const int ly0 = bY*4 - 1;          // 6 latent rows

    const float rc0 = cell[0] * 96.0f;
    const float rc1 = cell[1] * 96.0f;

    const float4* w64p = (const float4*)(W0 + 64*64);
    const float4* w65p = (const float4*)(W0 + 65*64);
    const float4* w66p = (const float4*)(W0 + 66*64);
    const float4* w67p = (const float4*)(W0 + 67*64);

    // ---- stage 6x4 latent patch: 24 rows x 64 items ----
    for (int idx = tid; idx < 1536; idx += 256) {
        const int r  = idx >> 6;
        const int o  = idx & 63;
        const int ry = r >> 2;
        const int rx = r & 3;
        const int gy = min(max(ly0 + ry, 0), 95);
        const int gx = min(max(lx0 + rx, 0), 95);
        const int src = gy*96 + gx;
        const float4* modv = (const float4*)(mod_ws + (size_t)src*256);
        if (o < 16) {
            const float4 f0 = ((const float4*)(f0_ws + (size_t)src*64))[o];
            const float4 s1 = modv[o];
            const float4 t1 = modv[32 + o];
            const float4 a  = w66p[o];
            const float4 b  = w67p[o];
            float4 v;
            v.x = fmaf(s1.x, fmaf(rc1, b.x, fmaf(rc0, a.x, f0.x)), t1.x);
            v.y = fmaf(s1.y, fmaf(rc1, b.y, fmaf(rc0, a.y, f0.y)), t1.y);
            v.z = fmaf(s1.z, fmaf(rc1, b.z, fmaf(rc0, a.z, f0.z)), t1.z);
            v.w = fmaf(s1.w, fmaf(rc1, b.w, fmaf(rc0, a.w, f0.w)), t1.w);
            *(float4*)(smem + r*ROWQ + o*4) = v;
        } else if (o < 32) {
            const int oo = o - 16;
            const float4 s1 = modv[oo];
            const float4 w  = w64p[oo];
            float4 v = {s1.x*w.x, s1.y*w.y, s1.z*w.z, s1.w*w.w};
            *(float4*)(smem + r*ROWQ + 64 + oo*4) = v;
        } else if (o < 48) {
            const int oo = o - 32;
            const float4 s1 = modv[oo];
            const float4 w  = w65p[oo];
            float4 v = {s1.x*w.x, s1.y*w.y, s1.z*w.z, s1.w*w.w};
            *(float4*)(smem + r*ROWQ + 128 + oo*4) = v;
        } else {
            const int oo = o - 48;             // 0..15
            const float4 s2 = modv[16 + oo];
            const float4 h2 = modv[48 + oo];
            #pragma unroll
            for (int j = 0; j < 4; ++j) {
                const int col = oo*4 + j;
                const int cc  = col & 15;
                const int nt  = col >> 4;
                const float sv = (j==0)?s2.x:(j==1)?s2.y:(j==2)?s2.z:s2.w;
                const float hv = (j==0)?h2.x:(j==1)?h2.y:(j==2)?h2.z:h2.w;
                smem[r*ROWQ + 192 + cc*4 + nt] = sv;
                smem[r*ROWQ + 256 + cc*4 + nt] = hv;
            }
        }
    }

    const int lane = tid & 63;
    const int wid  = tid >> 6;
    const int c    = lane & 15;
    const int kg   = lane >> 4;

    // per-wave constants: W1 frags from wsw (8 b128 loads)
    const short* w1f = wsw + (size_t)424*512;
    short8 Bh[4][2];
    #pragma unroll
    for (int kt = 0; kt < 2; ++kt)
        #pragma unroll
        for (int nt = 0; nt < 4; ++nt)
            Bh[nt][kt] = *(const short8*)(w1f + (size_t)(kt*4 + nt)*512 + lane*8);

    float b1c[4];
    float w2r[4][3];
    #pragma unroll
    for (int nt = 0; nt < 4; ++nt) {
        b1c[nt] = b1[nt*16 + c];
        w2r[nt][0] = W2[(nt*16 + c)*3 + 0];
        w2r[nt][1] = W2[(nt*16 + c)*3 + 1];
        w2r[nt][2] = W2[(nt*16 + c)*3 + 2];
    }
    const float b2v0 = b2[0], b2v1 = b2[1], b2v2 = b2[2];

    __syncthreads();

    const int Xw   = X0 + (wid & 1)*4;
    const int Yw   = Y0 + (wid >> 1)*8;
    const int qxA  = c >> 2;
    const int tapA = c & 3;
    const float vxA = (tapA < 2) ? -1.0f : 1.0f;
    const float vyA = (tapA & 1) ? 1.0f : -1.0f;

    // m-invariant x-axis tap math
    const float cxA = ((float)(Xw + qxA) + 0.5f) * INV192 - 1.0f;
    const float cxE = ((float)(Xw + kg)  + 0.5f) * INV192 - 1.0f;
    int ixA; float r1A;
    AXCALC(cxA, vyA, ixA, r1A)
    const int ixAc = ixA - lx0;
    int ixm, ixp; float r1m, r1p;
    AXCALC(cxE, -1.0f, ixm, r1m)
    AXCALC(cxE,  1.0f, ixp, r1p)

    for (int mm = 0; mm < 4; ++mm) {
        const int qyA_ = Yw + 2*mm;
        const int qyB_ = Yw + 2*mm + 1;

        EPI_CALC(A, qyA_)
        EPI_CALC(B, qyB_)
        ALOAD(A)
        ALOAD(B)
        EPI_LOAD(A)
        EPI_LOAD(B)
        APACK(A)
        APACK(B)
        MFMA_C(A)
        MFMA_C(B)
        EPIL(A, qyA_)
        EPIL(B, qyB_)
    }
}

extern "C" void kernel_launch(void* const* d_in, const int* in_sizes, int n_in,
                              void* d_out, int out_size, void* d_ws, size_t ws_size,
                              hipStream_t stream) {
    const float* feat  = (const float*)d_in[0];
    const float* cell  = (const float*)d_in[2];
    const float* Wh1   = (const float*)d_in[3];
    const float* bh1   = (const float*)d_in[4];
    const float* Wh2   = (const float*)d_in[5];
    const float* bh2   = (const float*)d_in[6];
    const float* W0    = (const float*)d_in[7];
    const float* b0    = (const float*)d_in[8];
    const float* W1    = (const float*)d_in[9];
    const float* b1    = (const float*)d_in[10];
    const float* W2    = (const float*)d_in[11];
    const float* b2    = (const float*)d_in[12];
    float* out = (float*)d_out;

    float* mod_ws = (float*)d_ws;                         // 9216*256 f32
    float* f0_ws  = (float*)d_ws + 9216*256;              // 9216*64  f32
    short* wsw    = (short*)((char*)d_ws + 11796480);     // 432 frags * 1024 B

    swizzle_kernel<<<dim3(108), dim3(256), 0, stream>>>(Wh1, Wh2, W0, W1, wsw);
    hyper_mfma<<<dim3(576), dim3(512), 0, stream>>>(
        feat, cell, Wh1, bh1, bh2, b0, wsw, mod_ws, f0_ws);
    query_kernel_v10<<<dim3(1152), dim3(256), 0, stream>>>(
        cell, W0, wsw, b1, W2, b2, mod_ws, f0_ws, out);
}